// Round 3
// baseline (508.632 us; speedup 1.0000x reference)
//
#include <hip/hip_runtime.h>
#include <hip/hip_bf16.h>

typedef __attribute__((ext_vector_type(8))) short short8_t;
typedef __attribute__((ext_vector_type(4))) float f32x4;
typedef __attribute__((ext_vector_type(4))) unsigned int u32x4;

#define KINST 100000
#define KPAD  100096   // 782 * 128
#define DIMIN 768
#define DIMEMB 512
#define DIMATTN 384

__device__ __forceinline__ unsigned short f2bf(float f) {
    unsigned int u = __builtin_bit_cast(unsigned int, f);
    u = u + 0x7FFFu + ((u >> 16) & 1u);       // RNE
    return (unsigned short)(u >> 16);
}
__device__ __forceinline__ unsigned int packbf(float a, float b) {
    return (unsigned int)f2bf(a) | ((unsigned int)f2bf(b) << 16);
}
__device__ __forceinline__ float bf2f(unsigned short h) {
    unsigned int u = ((unsigned int)h) << 16;
    return __builtin_bit_cast(float, u);
}
__device__ __forceinline__ float fast_tanh(float x) {
    const float e2 = __expf(2.f * x);
    return (e2 - 1.f) * __builtin_amdgcn_rcpf(e2 + 1.f);
}
// async global->LDS, 16B per lane. LDS dest = firstlane base + lane*16.
__device__ __forceinline__ void gll16(const unsigned short* g, unsigned short* l) {
    __builtin_amdgcn_global_load_lds(
        (const __attribute__((address_space(1))) unsigned int*)g,
        (__attribute__((address_space(3))) unsigned int*)l, 16, 0, 0);
}

// ---------------- prep: swizzled, K-tiled bf16 weights ----------------
// WpTs: [t<12][n<512][cs<8][e<8], cs = c ^ (n&7), value = bf16(Wproj[(t*64+c*8+e)*512 + n])
// W1Ts: [t<8][n<384][cs<8][e<8],  cs = c ^ (n&7), value = bf16(W1[(t*64+c*8+e)*384 + n])
__global__ __launch_bounds__(256) void k_prep(
    const float* __restrict__ Wproj, const float* __restrict__ W1,
    unsigned short* __restrict__ WpTs, unsigned short* __restrict__ W1Ts)
{
    const int idx = blockIdx.x * 256 + threadIdx.x;
    if (idx < 49152) {                 // 12*8*512
        const int t = idx >> 12, r = idx & 4095;
        const int c = r >> 9, n = r & 511;
        short8_t v;
        #pragma unroll
        for (int e = 0; e < 8; ++e)
            v[e] = (short)f2bf(Wproj[(size_t)(t * 64 + c * 8 + e) * DIMEMB + n]);
        *(short8_t*)&WpTs[t * 32768 + n * 64 + ((c ^ (n & 7)) << 3)] = v;
    } else {
        const int j = idx - 49152;     // < 24576 = 8*8*384
        const int t = j / 3072, r = j % 3072;
        const int c = r / 384, n = r % 384;
        short8_t v;
        #pragma unroll
        for (int e = 0; e < 8; ++e)
            v[e] = (short)f2bf(W1[(size_t)(t * 64 + c * 8 + e) * DIMATTN + n]);
        *(short8_t*)&W1Ts[t * 24576 + n * 64 + ((c ^ (n & 7)) << 3)] = v;
    }
}

// ---------------- GEMM1: H = relu(X @ Wp + b); BM=128, BN=512, BK=64 ----------------
// A (X) global->reg->bf16 frags; B via global_load_lds double-buffered, swizzled.
__global__ __launch_bounds__(512) void k_gemm1(
    const float* __restrict__ X,
    const unsigned short* __restrict__ WpTs,
    const float* __restrict__ bproj,
    unsigned short* __restrict__ H)
{
    __shared__ unsigned short Bs[2][32768];   // 2 x 64KB
    const int tid = threadIdx.x;
    const int lane = tid & 63, w = tid >> 6;
    const int wr = w >> 2, wc = w & 3;        // 2x4 waves: 64 rows x 128 cols each
    const int g = lane >> 4, fr = lane & 15;
    const int brow = blockIdx.x * 128;

    const float* xrow[4];
    #pragma unroll
    for (int i = 0; i < 4; ++i) {
        int r = brow + wr * 64 + i * 16 + fr;
        if (r >= KINST) r = KINST - 1;
        xrow[i] = X + (size_t)r * DIMIN + g * 8;
    }
    const unsigned short* gb = WpTs + (w * 8) * 512 + lane * 8;
    unsigned short* lb0 = &Bs[0][w * 8 * 512 + lane * 8];
    unsigned short* lb1 = &Bs[1][w * 8 * 512 + lane * 8];

    f32x4 acc[4][8] = {};

    #pragma unroll
    for (int q = 0; q < 8; ++q)               // prologue: B(0) -> buf0
        gll16(gb + q * 512, lb0 + q * 512);
    __syncthreads();

    for (int t = 0; t < 12; ++t) {
        const int buf = t & 1;
        // A(t): 16 x float4 -> bf16 frags
        short8_t abf[4][2];
        {
            float4 av[4][2][2];
            #pragma unroll
            for (int i = 0; i < 4; ++i)
                #pragma unroll
                for (int kk = 0; kk < 2; ++kk) {
                    av[i][kk][0] = *(const float4*)(xrow[i] + t * 64 + kk * 32);
                    av[i][kk][1] = *(const float4*)(xrow[i] + t * 64 + kk * 32 + 4);
                }
            // issue B(t+1) into other buffer (flies during convert+MFMA)
            if (t + 1 < 12) {
                const unsigned short* gsrc = gb + (t + 1) * 32768;
                unsigned short* ldst = buf ? lb0 : lb1;
                #pragma unroll
                for (int q = 0; q < 8; ++q)
                    gll16(gsrc + q * 512, ldst + q * 512);
            }
            #pragma unroll
            for (int i = 0; i < 4; ++i)
                #pragma unroll
                for (int kk = 0; kk < 2; ++kk) {
                    u32x4 p;
                    p[0] = packbf(av[i][kk][0].x, av[i][kk][0].y);
                    p[1] = packbf(av[i][kk][0].z, av[i][kk][0].w);
                    p[2] = packbf(av[i][kk][1].x, av[i][kk][1].y);
                    p[3] = packbf(av[i][kk][1].z, av[i][kk][1].w);
                    abf[i][kk] = __builtin_bit_cast(short8_t, p);
                }
        }
        #pragma unroll
        for (int kk = 0; kk < 2; ++kk) {
            const int csw = (kk << 2) + g;
            #pragma unroll
            for (int j = 0; j < 8; ++j) {
                const int row = wc * 128 + j * 16 + fr;
                const short8_t bf = *(const short8_t*)&Bs[buf][row * 64 + ((csw ^ (fr & 7)) << 3)];
                #pragma unroll
                for (int i = 0; i < 4; ++i)
                    acc[i][j] = __builtin_amdgcn_mfma_f32_16x16x32_bf16(abf[i][kk], bf, acc[i][j], 0, 0, 0);
            }
        }
        __syncthreads();
    }

    #pragma unroll
    for (int j = 0; j < 8; ++j) {
        const int col = wc * 128 + j * 16 + fr;
        const float bias = bproj[col];
        #pragma unroll
        for (int i = 0; i < 4; ++i) {
            const int rb = brow + wr * 64 + i * 16 + g * 4;
            #pragma unroll
            for (int r = 0; r < 4; ++r) {
                const int row = rb + r;
                const float v = fmaxf(acc[i][j][r] + bias, 0.f);
                H[(size_t)row * DIMEMB + col] = (row < KINST) ? f2bf(v) : (unsigned short)0;
            }
        }
    }
}

// -------- GEMM2 + attention score + fused pooling; BM=128, BN=384, BK=64 --------
__global__ __launch_bounds__(512) void k_gemm2(
    const unsigned short* __restrict__ H,
    const unsigned short* __restrict__ W1Ts,
    const float* __restrict__ b1,
    const float* __restrict__ W2,
    const float* __restrict__ b2,
    float* __restrict__ Spart,
    float* __restrict__ Mpart)
{
    __shared__ unsigned short Bs[2][24576];   // 2 x 48KB
    __shared__ float sred[4][128];
    __shared__ float Elds[128];
    __shared__ float ssum[8];
    __shared__ float red[8][512];
    const int tid = threadIdx.x;
    const int lane = tid & 63, w = tid >> 6;
    const int wr = w >> 2, wc = w & 3;        // 2x4 waves: 64 rows x 96 cols each
    const int g = lane >> 4, fr = lane & 15;
    const int brow = blockIdx.x * 128;

    const unsigned short* hrow[4];
    #pragma unroll
    for (int i = 0; i < 4; ++i)
        hrow[i] = H + (size_t)(brow + wr * 64 + i * 16 + fr) * DIMEMB + g * 8;

    const unsigned short* gb = W1Ts + (w * 6) * 512 + lane * 8;
    unsigned short* lb0 = &Bs[0][w * 6 * 512 + lane * 8];
    unsigned short* lb1 = &Bs[1][w * 6 * 512 + lane * 8];

    f32x4 acc[4][6] = {};

    #pragma unroll
    for (int q = 0; q < 6; ++q)               // prologue: B(0) -> buf0
        gll16(gb + q * 512, lb0 + q * 512);
    __syncthreads();

    for (int t = 0; t < 8; ++t) {
        const int buf = t & 1;
        short8_t af[4][2];
        #pragma unroll
        for (int i = 0; i < 4; ++i)
            #pragma unroll
            for (int kk = 0; kk < 2; ++kk)
                af[i][kk] = *(const short8_t*)(hrow[i] + t * 64 + kk * 32);
        if (t + 1 < 8) {
            const unsigned short* gsrc = gb + (t + 1) * 24576;
            unsigned short* ldst = buf ? lb0 : lb1;
            #pragma unroll
            for (int q = 0; q < 6; ++q)
                gll16(gsrc + q * 512, ldst + q * 512);
        }
        #pragma unroll
        for (int kk = 0; kk < 2; ++kk) {
            const int csw = (kk << 2) + g;
            #pragma unroll
            for (int j = 0; j < 6; ++j) {
                const int row = wc * 96 + j * 16 + fr;
                const short8_t bf = *(const short8_t*)&Bs[buf][row * 64 + ((csw ^ (fr & 7)) << 3)];
                #pragma unroll
                for (int i = 0; i < 4; ++i)
                    acc[i][j] = __builtin_amdgcn_mfma_f32_16x16x32_bf16(af[i][kk], bf, acc[i][j], 0, 0, 0);
            }
        }
        __syncthreads();
    }

    // per-lane partial score over this wave's 96 cols
    float ps[4][4] = {};
    #pragma unroll
    for (int j = 0; j < 6; ++j) {
        const int col = wc * 96 + j * 16 + fr;
        const float bb = b1[col], ww = W2[col];
        #pragma unroll
        for (int i = 0; i < 4; ++i)
            #pragma unroll
            for (int r = 0; r < 4; ++r)
                ps[i][r] += fast_tanh(acc[i][j][r] + bb) * ww;
    }
    #pragma unroll
    for (int off = 1; off < 16; off <<= 1)
        #pragma unroll
        for (int i = 0; i < 4; ++i)
            #pragma unroll
            for (int r = 0; r < 4; ++r)
                ps[i][r] += __shfl_xor(ps[i][r], off, 64);
    if (fr == 0) {
        #pragma unroll
        for (int i = 0; i < 4; ++i)
            #pragma unroll
            for (int r = 0; r < 4; ++r)
                sred[wc][wr * 64 + i * 16 + g * 4 + r] = ps[i][r];
    }
    __syncthreads();
    float myE = 0.f;
    if (tid < 128) {
        const int row = brow + tid;
        const float s = sred[0][tid] + sred[1][tid] + sred[2][tid] + sred[3][tid] + b2[0];
        const float e = __expf(s);
        const float eg = (row < KINST) ? e : 0.f;
        Elds[tid] = eg;
        myE = eg;
    }
    #pragma unroll
    for (int off = 1; off < 64; off <<= 1) myE += __shfl_xor(myE, off, 64);
    if (lane == 0) ssum[w] = myE;
    __syncthreads();
    if (tid == 0) {
        float tacc = 0.f;
        #pragma unroll
        for (int i = 0; i < 8; ++i) tacc += ssum[i];
        Spart[blockIdx.x] = tacc;
    }

    // fused pooling: re-read this block's H (L2/L3-hot), weight by Elds
    float pa[8] = {};
    const int hb = lane << 3;
    #pragma unroll 4
    for (int i = 0; i < 16; ++i) {
        const int r = (w << 4) + i;
        const float e = Elds[r];
        const short8_t v = *(const short8_t*)(H + (size_t)(brow + r) * DIMEMB + hb);
        #pragma unroll
        for (int j = 0; j < 8; ++j)
            pa[j] += e * bf2f((unsigned short)v[j]);
    }
    #pragma unroll
    for (int j = 0; j < 8; ++j) red[w][hb + j] = pa[j];
    __syncthreads();
    float s2 = 0.f;
    #pragma unroll
    for (int k = 0; k < 8; ++k) s2 += red[k][tid];
    Mpart[(size_t)blockIdx.x * DIMEMB + tid] = s2;
}

// ---------------- head: reduce Spart/Mpart, router, top-5, logits ----------------
__global__ __launch_bounds__(1024) void k_head(
    const float* __restrict__ Spart,   // [782]
    const float* __restrict__ Mpart,   // [782][512]
    const float* __restrict__ Wr,      // [512][13]
    const float* __restrict__ Xtfl,    // [13][512]
    const float* __restrict__ Wp,      // [512][2]
    const float* __restrict__ bp,      // [2]
    float* __restrict__ outp)
{
    __shared__ float Mlds[512];
    __shared__ float red2[2][512];
    __shared__ float logits[13];
    __shared__ float wsel[5];
    __shared__ int isel[5];
    __shared__ float Slds;
    __shared__ float swred[16];
    __shared__ float r0s[16], r1s[16];
    const int tid = threadIdx.x, lane = tid & 63, w = tid >> 6;
    const int half = tid >> 9, d = tid & 511;

    float s = 0.f;
    for (int i = tid; i < 782; i += 1024) s += Spart[i];
    #pragma unroll
    for (int off = 1; off < 64; off <<= 1) s += __shfl_xor(s, off, 64);
    if (lane == 0) swred[w] = s;

    float m = 0.f;
    #pragma unroll 4
    for (int b = half; b < 782; b += 2) m += Mpart[(size_t)b * 512 + d];
    red2[half][d] = m;

    __syncthreads();
    if (tid == 0) {
        float t = 0.f;
        #pragma unroll
        for (int i = 0; i < 16; ++i) t += swred[i];
        Slds = t;
    }
    __syncthreads();
    if (tid < 512) {
        Mlds[tid] = (red2[0][tid] + red2[1][tid]) / Slds;
    }
    __syncthreads();
    if (tid < 13) {
        float l = 0.f;
        for (int dd = 0; dd < 512; ++dd) l += Mlds[dd] * Wr[dd * 13 + tid];
        logits[tid] = l;
    }
    __syncthreads();
    if (tid == 0) {
        float mx = -1e30f;
        for (int i = 0; i < 13; ++i) mx = fmaxf(mx, logits[i]);
        float pe[13]; float sum = 0.f;
        for (int i = 0; i < 13; ++i) { pe[i] = __expf(logits[i] - mx); sum += pe[i]; }
        unsigned used = 0;
        for (int t = 0; t < 5; ++t) {
            int bi = 0; float bv = -1.f;
            for (int i = 0; i < 13; ++i)
                if (!((used >> i) & 1u) && pe[i] > bv) { bv = pe[i]; bi = i; }
            used |= (1u << bi);
            wsel[t] = bv / sum;
            isel[t] = bi;
        }
    }
    __syncthreads();
    float p0 = 0.f, p1 = 0.f;
    if (tid < 512) {
        float mo = 0.f;
        #pragma unroll
        for (int t = 0; t < 5; ++t) mo += wsel[t] * Xtfl[isel[t] * 512 + tid];
        p0 = mo * Wp[tid * 2 + 0];
        p1 = mo * Wp[tid * 2 + 1];
    }
    #pragma unroll
    for (int off = 1; off < 64; off <<= 1) {
        p0 += __shfl_xor(p0, off, 64);
        p1 += __shfl_xor(p1, off, 64);
    }
    if (lane == 0) { r0s[w] = p0; r1s[w] = p1; }
    __syncthreads();
    if (tid == 0) {
        float a = bp[0], b = bp[1];
        for (int i = 0; i < 16; ++i) { a += r0s[i]; b += r1s[i]; }
        outp[0] = a; outp[1] = b;
    }
}

extern "C" void kernel_launch(void* const* d_in, const int* in_sizes, int n_in,
                              void* d_out, int out_size, void* d_ws, size_t ws_size,
                              hipStream_t stream)
{
    const float* Xtfl  = (const float*)d_in[0];
    const float* X     = (const float*)d_in[1];
    const float* Wproj = (const float*)d_in[2];
    const float* bproj = (const float*)d_in[3];
    const float* W1    = (const float*)d_in[4];
    const float* b1    = (const float*)d_in[5];
    const float* W2    = (const float*)d_in[6];
    const float* b2    = (const float*)d_in[7];
    const float* Wr    = (const float*)d_in[8];
    const float* Wp    = (const float*)d_in[9];
    const float* bp    = (const float*)d_in[10];
    float* out = (float*)d_out;

    // ws layout (~105 MiB total)
    char* ws = (char*)d_ws;
    size_t off = 0;
    unsigned short* H    = (unsigned short*)(ws + off); off += (size_t)KPAD * DIMEMB * 2;
    unsigned short* WpTs = (unsigned short*)(ws + off); off += (size_t)DIMEMB * DIMIN * 2;
    unsigned short* W1Ts = (unsigned short*)(ws + off); off += (size_t)DIMATTN * DIMEMB * 2;
    float* Spart = (float*)(ws + off); off += 4096;
    float* Mpart = (float*)(ws + off); off += (size_t)782 * DIMEMB * 4;

    k_prep<<<288, 256, 0, stream>>>(Wproj, W1, WpTs, W1Ts);
    k_gemm1<<<782, 512, 0, stream>>>(X, WpTs, bproj, H);
    k_gemm2<<<782, 512, 0, stream>>>(H, W1Ts, b1, W2, b2, Spart, Mpart);
    k_head<<<1, 1024, 0, stream>>>(Spart, Mpart, Wr, Xtfl, Wp, bp, out);
}

// Round 4
// 428.952 us; speedup vs baseline: 1.1858x; 1.1858x over previous
//
#include <hip/hip_runtime.h>
#include <hip/hip_bf16.h>

typedef __attribute__((ext_vector_type(8))) short short8_t;
typedef __attribute__((ext_vector_type(4))) float f32x4;
typedef __attribute__((ext_vector_type(4))) unsigned int u32x4;

#define KINST 100000
#define KPAD  100096   // 782 * 128
#define DIMIN 768
#define DIMEMB 512
#define DIMATTN 384

__device__ __forceinline__ unsigned short f2bf(float f) {
    unsigned int u = __builtin_bit_cast(unsigned int, f);
    u = u + 0x7FFFu + ((u >> 16) & 1u);       // RNE
    return (unsigned short)(u >> 16);
}
__device__ __forceinline__ unsigned int packbf(float a, float b) {
    return (unsigned int)f2bf(a) | ((unsigned int)f2bf(b) << 16);
}
__device__ __forceinline__ float bf2f(unsigned short h) {
    unsigned int u = ((unsigned int)h) << 16;
    return __builtin_bit_cast(float, u);
}
__device__ __forceinline__ float fast_tanh(float x) {
    const float e2 = __expf(2.f * x);
    return (e2 - 1.f) * __builtin_amdgcn_rcpf(e2 + 1.f);
}
// async global->LDS, 16B per lane. LDS dest must be wave-uniform base + lane*16.
__device__ __forceinline__ void gll16(const unsigned short* g, unsigned short* l) {
    __builtin_amdgcn_global_load_lds(
        (const __attribute__((address_space(1))) unsigned int*)g,
        (__attribute__((address_space(3))) unsigned int*)l, 16, 0, 0);
}

// ---------------- prep: swizzled, K-tiled bf16 weights (verified round 3) ----------------
// WpTs: [t<12][n<512][cs<8][e<8], cs = c ^ (n&7), value = bf16(Wproj[(t*64+c*8+e)*512 + n])
// W1Ts: [t<8][n<384][cs<8][e<8],  cs = c ^ (n&7), value = bf16(W1[(t*64+c*8+e)*384 + n])
__global__ __launch_bounds__(256) void k_prep(
    const float* __restrict__ Wproj, const float* __restrict__ W1,
    unsigned short* __restrict__ WpTs, unsigned short* __restrict__ W1Ts)
{
    const int idx = blockIdx.x * 256 + threadIdx.x;
    if (idx < 49152) {                 // 12*8*512
        const int t = idx >> 12, r = idx & 4095;
        const int c = r >> 9, n = r & 511;
        short8_t v;
        #pragma unroll
        for (int e = 0; e < 8; ++e)
            v[e] = (short)f2bf(Wproj[(size_t)(t * 64 + c * 8 + e) * DIMEMB + n]);
        *(short8_t*)&WpTs[t * 32768 + n * 64 + ((c ^ (n & 7)) << 3)] = v;
    } else {
        const int j = idx - 49152;     // < 24576 = 8*8*384
        const int t = j / 3072, r = j % 3072;
        const int c = r / 384, n = r % 384;
        short8_t v;
        #pragma unroll
        for (int e = 0; e < 8; ++e)
            v[e] = (short)f2bf(W1[(size_t)(t * 64 + c * 8 + e) * DIMATTN + n]);
        *(short8_t*)&W1Ts[t * 24576 + n * 64 + ((c ^ (n & 7)) << 3)] = v;
    }
}

// ---------------- GEMM1: H = relu(X @ Wp + b); BM=128, BN=128, BK=64 ----------------
// H stored SWIZZLED: element (row,col) at row*512 + (col>>6)*64 + ((((col>>3)&7) ^ (row&7))<<3) + (col&7)
__global__ __launch_bounds__(256) void k_gemm1(
    const float* __restrict__ X,
    const unsigned short* __restrict__ WpTs,
    const float* __restrict__ bproj,
    unsigned short* __restrict__ H)
{
    __shared__ unsigned short As[2][8192];   // 2 x 16KB, XOR-swizzled
    __shared__ unsigned short Bs[2][8192];   // 2 x 16KB, pre-swizzled global
    const int tid = threadIdx.x;
    const int lane = tid & 63, w = tid >> 6;
    const int wr = w >> 1, wc = w & 1;       // 2x2 waves, 64x64 tiles
    const int g = lane >> 4, fr = lane & 15;
    const int bcol = blockIdx.x * 128;
    const int brow = blockIdx.y * 128;

    // A staging: 2 threads per row, 32 floats each, coalesced
    const int arow = tid >> 1, ahalf = tid & 1;
    int agr = brow + arow; if (agr >= KINST) agr = KINST - 1;
    const float* xsrc = X + (size_t)agr * DIMIN + ahalf * 32;
    const int axor = arow & 7;

    // B staging via global_load_lds: per wave 32 rows, 4 calls
    const unsigned short* gB = WpTs + (size_t)(bcol + w * 32 + (lane >> 3)) * 64 + (lane & 7) * 8;
    const int lBoff = w * 2048 + lane * 8;

    f32x4 acc[4][4] = {};
    float4 av[8];

    // prologue: B(0), A(0) staged; A(1) in regs
    #pragma unroll
    for (int q = 0; q < 4; ++q) gll16(gB + q * 512, &Bs[0][lBoff + q * 512]);
    #pragma unroll
    for (int q = 0; q < 8; ++q) av[q] = *(const float4*)(xsrc + q * 4);
    #pragma unroll
    for (int q = 0; q < 4; ++q) {
        u32x4 p;
        p[0] = packbf(av[2*q].x, av[2*q].y);   p[1] = packbf(av[2*q].z, av[2*q].w);
        p[2] = packbf(av[2*q+1].x, av[2*q+1].y); p[3] = packbf(av[2*q+1].z, av[2*q+1].w);
        *(u32x4*)&As[0][arow * 64 + (((ahalf * 4 + q) ^ axor) << 3)] = p;
    }
    #pragma unroll
    for (int q = 0; q < 8; ++q) av[q] = *(const float4*)(xsrc + 64 + q * 4);
    __syncthreads();

    for (int t = 0; t < 12; ++t) {
        const int buf = t & 1;
        if (t < 11) {
            // issue B(t+1) into other buffer (flies during MFMA phase)
            #pragma unroll
            for (int q = 0; q < 4; ++q)
                gll16(gB + (size_t)(t + 1) * 32768 + q * 512, &Bs[buf ^ 1][lBoff + q * 512]);
            // write As(t+1) from regs (loaded last iteration)
            #pragma unroll
            for (int q = 0; q < 4; ++q) {
                u32x4 p;
                p[0] = packbf(av[2*q].x, av[2*q].y);   p[1] = packbf(av[2*q].z, av[2*q].w);
                p[2] = packbf(av[2*q+1].x, av[2*q+1].y); p[3] = packbf(av[2*q+1].z, av[2*q+1].w);
                *(u32x4*)&As[buf ^ 1][arow * 64 + (((ahalf * 4 + q) ^ axor) << 3)] = p;
            }
            // issue A(t+2) loads (fly during MFMA)
            if (t < 10) {
                #pragma unroll
                for (int q = 0; q < 8; ++q) av[q] = *(const float4*)(xsrc + (t + 2) * 64 + q * 4);
            }
        }
        __builtin_amdgcn_s_setprio(1);
        #pragma unroll
        for (int kk = 0; kk < 2; ++kk) {
            short8_t af[4];
            #pragma unroll
            for (int i = 0; i < 4; ++i) {
                const int row = wr * 64 + i * 16 + fr;
                af[i] = *(const short8_t*)&As[buf][row * 64 + (((kk * 4 + g) ^ (fr & 7)) << 3)];
            }
            #pragma unroll
            for (int j = 0; j < 4; ++j) {
                const int rowb = wc * 64 + j * 16 + fr;
                const short8_t bf = *(const short8_t*)&Bs[buf][rowb * 64 + (((kk * 4 + g) ^ (fr & 7)) << 3)];
                #pragma unroll
                for (int i = 0; i < 4; ++i)
                    acc[i][j] = __builtin_amdgcn_mfma_f32_16x16x32_bf16(af[i], bf, acc[i][j], 0, 0, 0);
            }
        }
        __builtin_amdgcn_s_setprio(0);
        if (t < 11) __syncthreads();
    }

    // epilogue: bias + relu, swizzled bf16 H store
    #pragma unroll
    for (int j = 0; j < 4; ++j) {
        const int col = bcol + wc * 64 + j * 16 + fr;
        const float bias = bproj[col];
        const int tile = (col >> 6) << 6, cc = (col >> 3) & 7, lo = col & 7;
        #pragma unroll
        for (int i = 0; i < 4; ++i) {
            const int rb = brow + wr * 64 + i * 16 + g * 4;
            #pragma unroll
            for (int r = 0; r < 4; ++r) {
                const int row = rb + r;
                const float v = fmaxf(acc[i][j][r] + bias, 0.f);
                H[(size_t)row * DIMEMB + tile + (((cc ^ (row & 7))) << 3) + lo] =
                    (row < KINST) ? f2bf(v) : (unsigned short)0;
            }
        }
    }
}

// -------- GEMM2 partial scores: Tpart[cb][row] = sum_{cols in cb} tanh(H@W1+b1)*W2 --------
__global__ __launch_bounds__(256) void k_gemm2(
    const unsigned short* __restrict__ H,
    const unsigned short* __restrict__ W1Ts,
    const float* __restrict__ b1,
    const float* __restrict__ W2,
    float* __restrict__ Tpart)
{
    __shared__ unsigned short As[2][8192];
    __shared__ unsigned short Bs[2][8192];
    __shared__ float sred[2][128];
    const int tid = threadIdx.x;
    const int lane = tid & 63, w = tid >> 6;
    const int wr = w >> 1, wc = w & 1;
    const int g = lane >> 4, fr = lane & 15;
    const int cb = blockIdx.x;               // 0..2
    const int brow = blockIdx.y * 128;
    const int bcol = cb * 128;

    const unsigned short* gA = H + (size_t)(brow + w * 32 + (lane >> 3)) * DIMEMB + (lane & 7) * 8;
    const unsigned short* gB = W1Ts + (size_t)(bcol + w * 32 + (lane >> 3)) * 64 + (lane & 7) * 8;
    const int loff = w * 2048 + lane * 8;

    f32x4 acc[4][4] = {};

    #pragma unroll
    for (int q = 0; q < 4; ++q) {
        gll16(gA + q * 4096, &As[0][loff + q * 512]);
        gll16(gB + q * 512,  &Bs[0][loff + q * 512]);
    }
    __syncthreads();

    for (int t = 0; t < 8; ++t) {
        const int buf = t & 1;
        if (t < 7) {
            #pragma unroll
            for (int q = 0; q < 4; ++q) {
                gll16(gA + (t + 1) * 64 + q * 4096,          &As[buf ^ 1][loff + q * 512]);
                gll16(gB + (size_t)(t + 1) * 24576 + q * 512, &Bs[buf ^ 1][loff + q * 512]);
            }
        }
        __builtin_amdgcn_s_setprio(1);
        #pragma unroll
        for (int kk = 0; kk < 2; ++kk) {
            short8_t af[4];
            #pragma unroll
            for (int i = 0; i < 4; ++i) {
                const int row = wr * 64 + i * 16 + fr;
                af[i] = *(const short8_t*)&As[buf][row * 64 + (((kk * 4 + g) ^ (fr & 7)) << 3)];
            }
            #pragma unroll
            for (int j = 0; j < 4; ++j) {
                const int rowb = wc * 64 + j * 16 + fr;
                const short8_t bf = *(const short8_t*)&Bs[buf][rowb * 64 + (((kk * 4 + g) ^ (fr & 7)) << 3)];
                #pragma unroll
                for (int i = 0; i < 4; ++i)
                    acc[i][j] = __builtin_amdgcn_mfma_f32_16x16x32_bf16(af[i], bf, acc[i][j], 0, 0, 0);
            }
        }
        __builtin_amdgcn_s_setprio(0);
        if (t < 7) __syncthreads();
    }

    // epilogue: tanh + W2 partial over this block's 128 cols
    float ps[4][4] = {};
    #pragma unroll
    for (int j = 0; j < 4; ++j) {
        const int col = bcol + wc * 64 + j * 16 + fr;
        const float bb = b1[col], ww = W2[col];
        #pragma unroll
        for (int i = 0; i < 4; ++i)
            #pragma unroll
            for (int r = 0; r < 4; ++r)
                ps[i][r] += fast_tanh(acc[i][j][r] + bb) * ww;
    }
    #pragma unroll
    for (int off = 1; off < 16; off <<= 1)
        #pragma unroll
        for (int i = 0; i < 4; ++i)
            #pragma unroll
            for (int r = 0; r < 4; ++r)
                ps[i][r] += __shfl_xor(ps[i][r], off, 64);
    if (fr == 0) {
        #pragma unroll
        for (int i = 0; i < 4; ++i)
            #pragma unroll
            for (int r = 0; r < 4; ++r)
                sred[wc][wr * 64 + i * 16 + g * 4 + r] = ps[i][r];
    }
    __syncthreads();
    if (tid < 128)
        Tpart[(size_t)cb * KPAD + brow + tid] = sred[0][tid] + sred[1][tid];
}

// ---------------- poolE: E=exp(sum Tpart + b2); Spart; Mpart = E·H pooling ----------------
__global__ __launch_bounds__(512) void k_poolE(
    const float* __restrict__ Tpart,
    const unsigned short* __restrict__ H,
    const float* __restrict__ b2,
    float* __restrict__ Spart,
    float* __restrict__ Mpart)
{
    __shared__ float Elds[1024];
    __shared__ float red[8][512];
    __shared__ float ssum[8];
    const int tid = threadIdx.x, lane = tid & 63, w = tid >> 6;
    const int base = blockIdx.x * 1024;
    const float bb = b2[0];
    float es = 0.f;
    #pragma unroll
    for (int u = 0; u < 2; ++u) {
        const int r = base + u * 512 + tid;
        float e = 0.f;
        if (r < KINST)
            e = __expf(Tpart[r] + Tpart[KPAD + r] + Tpart[2 * KPAD + r] + bb);
        Elds[u * 512 + tid] = e;
        es += e;
    }
    #pragma unroll
    for (int off = 1; off < 64; off <<= 1) es += __shfl_xor(es, off, 64);
    if (lane == 0) ssum[w] = es;
    __syncthreads();
    if (tid == 0) {
        float t = 0.f;
        #pragma unroll
        for (int i = 0; i < 8; ++i) t += ssum[i];
        Spart[blockIdx.x] = t;
    }

    // pooling over swizzled H: lane owns cols lane*8..lane*8+7
    float pa[8] = {};
    const int tile = (lane >> 3) << 6, cf = lane & 7;
    for (int i = 0; i < 128; ++i) {
        const int lr = i * 8 + w;
        const float e = Elds[lr];
        if (e != 0.f) {                       // wave-uniform (lr same across lanes)
            const int r = base + lr;
            const short8_t v = *(const short8_t*)(H + (size_t)r * DIMEMB + tile + ((cf ^ (r & 7)) << 3));
            #pragma unroll
            for (int j = 0; j < 8; ++j) pa[j] += e * bf2f((unsigned short)v[j]);
        }
    }
    #pragma unroll
    for (int j = 0; j < 8; ++j) red[w][lane * 8 + j] = pa[j];
    __syncthreads();
    float s2 = 0.f;
    #pragma unroll
    for (int k = 0; k < 8; ++k) s2 += red[k][tid];
    Mpart[(size_t)blockIdx.x * DIMEMB + tid] = s2;
}

// ---------------- head: reduce Spart/Mpart, router, top-5, logits ----------------
__global__ __launch_bounds__(512) void k_head(
    const float* __restrict__ Spart,   // [98]
    const float* __restrict__ Mpart,   // [98][512]
    const float* __restrict__ Wr,      // [512][13]
    const float* __restrict__ Xtfl,    // [13][512]
    const float* __restrict__ Wp,      // [512][2]
    const float* __restrict__ bp,      // [2]
    float* __restrict__ outp)
{
    __shared__ float Mlds[512];
    __shared__ float logits[13];
    __shared__ float wsel[5];
    __shared__ int isel[5];
    __shared__ float Slds;
    __shared__ float swred[8];
    __shared__ float r0s[8], r1s[8];
    const int tid = threadIdx.x, lane = tid & 63, w = tid >> 6;

    float s = 0.f;
    if (tid < 98) s = Spart[tid];
    #pragma unroll
    for (int off = 1; off < 64; off <<= 1) s += __shfl_xor(s, off, 64);
    if (lane == 0) swred[w] = s;

    float m = 0.f;
    #pragma unroll 2
    for (int b = 0; b < 98; ++b) m += Mpart[(size_t)b * 512 + tid];

    __syncthreads();
    if (tid == 0) {
        float t = 0.f;
        #pragma unroll
        for (int i = 0; i < 8; ++i) t += swred[i];
        Slds = t;
    }
    __syncthreads();
    Mlds[tid] = m / Slds;
    __syncthreads();
    if (tid < 13) {
        float l = 0.f;
        for (int dd = 0; dd < 512; ++dd) l += Mlds[dd] * Wr[dd * 13 + tid];
        logits[tid] = l;
    }
    __syncthreads();
    if (tid == 0) {
        float mx = -1e30f;
        for (int i = 0; i < 13; ++i) mx = fmaxf(mx, logits[i]);
        float pe[13]; float sum = 0.f;
        for (int i = 0; i < 13; ++i) { pe[i] = __expf(logits[i] - mx); sum += pe[i]; }
        unsigned used = 0;
        for (int t = 0; t < 5; ++t) {
            int bi = 0; float bv = -1.f;
            for (int i = 0; i < 13; ++i)
                if (!((used >> i) & 1u) && pe[i] > bv) { bv = pe[i]; bi = i; }
            used |= (1u << bi);
            wsel[t] = bv / sum;
            isel[t] = bi;
        }
    }
    __syncthreads();
    float mo = 0.f;
    #pragma unroll
    for (int t = 0; t < 5; ++t) mo += wsel[t] * Xtfl[isel[t] * 512 + tid];
    float p0 = mo * Wp[tid * 2 + 0];
    float p1 = mo * Wp[tid * 2 + 1];
    #pragma unroll
    for (int off = 1; off < 64; off <<= 1) {
        p0 += __shfl_xor(p0, off, 64);
        p1 += __shfl_xor(p1, off, 64);
    }
    if (lane == 0) { r0s[w] = p0; r1s[w] = p1; }
    __syncthreads();
    if (tid == 0) {
        float a = bp[0], b = bp[1];
        for (int i = 0; i < 8; ++i) { a += r0s[i]; b += r1s[i]; }
        outp[0] = a; outp[1] = b;
    }
}

extern "C" void kernel_launch(void* const* d_in, const int* in_sizes, int n_in,
                              void* d_out, int out_size, void* d_ws, size_t ws_size,
                              hipStream_t stream)
{
    const float* Xtfl  = (const float*)d_in[0];
    const float* X     = (const float*)d_in[1];
    const float* Wproj = (const float*)d_in[2];
    const float* bproj = (const float*)d_in[3];
    const float* W1    = (const float*)d_in[4];
    const float* b1    = (const float*)d_in[5];
    const float* W2    = (const float*)d_in[6];
    const float* b2    = (const float*)d_in[7];
    const float* Wr    = (const float*)d_in[8];
    const float* Wp    = (const float*)d_in[9];
    const float* bp    = (const float*)d_in[10];
    float* out = (float*)d_out;

    // ws layout (~105 MiB total)
    char* ws = (char*)d_ws;
    size_t off = 0;
    unsigned short* H    = (unsigned short*)(ws + off); off += (size_t)KPAD * DIMEMB * 2;
    unsigned short* WpTs = (unsigned short*)(ws + off); off += (size_t)DIMEMB * DIMIN * 2;
    unsigned short* W1Ts = (unsigned short*)(ws + off); off += (size_t)DIMATTN * DIMEMB * 2;
    float* Tpart = (float*)(ws + off); off += (size_t)3 * KPAD * 4;
    float* Spart = (float*)(ws + off); off += 1024;
    float* Mpart = (float*)(ws + off); off += (size_t)98 * DIMEMB * 4;

    k_prep<<<288, 256, 0, stream>>>(Wproj, W1, WpTs, W1Ts);
    k_gemm1<<<dim3(4, 782), 256, 0, stream>>>(X, WpTs, bproj, H);
    k_gemm2<<<dim3(3, 782), 256, 0, stream>>>(H, W1Ts, b1, W2, Tpart);
    k_poolE<<<98, 512, 0, stream>>>(Tpart, H, b2, Spart, Mpart);
    k_head<<<1, 512, 0, stream>>>(Spart, Mpart, Wr, Xtfl, Wp, bp, out);
}

// Round 5
// 333.747 us; speedup vs baseline: 1.5240x; 1.2853x over previous
//
#include <hip/hip_runtime.h>
#include <hip/hip_bf16.h>

typedef __attribute__((ext_vector_type(8))) short short8_t;
typedef __attribute__((ext_vector_type(4))) float f32x4;
typedef __attribute__((ext_vector_type(4))) unsigned int u32x4;

#define KINST 100000
#define KPAD  100096   // 782 * 128
#define DIMIN 768
#define DIMEMB 512
#define DIMATTN 384

__device__ __forceinline__ unsigned short f2bf(float f) {
    unsigned int u = __builtin_bit_cast(unsigned int, f);
    u = u + 0x7FFFu + ((u >> 16) & 1u);       // RNE
    return (unsigned short)(u >> 16);
}
__device__ __forceinline__ unsigned int packbf(float a, float b) {
    return (unsigned int)f2bf(a) | ((unsigned int)f2bf(b) << 16);
}
__device__ __forceinline__ float bf2f(unsigned short h) {
    unsigned int u = ((unsigned int)h) << 16;
    return __builtin_bit_cast(float, u);
}
__device__ __forceinline__ float fast_tanh(float x) {
    const float e2 = __expf(2.f * x);
    return (e2 - 1.f) * __builtin_amdgcn_rcpf(e2 + 1.f);
}
// async global->LDS, 16B per lane. LDS dest must be wave-uniform base + lane*16.
__device__ __forceinline__ void gll16(const unsigned short* g, unsigned short* l) {
    __builtin_amdgcn_global_load_lds(
        (const __attribute__((address_space(1))) unsigned int*)g,
        (__attribute__((address_space(3))) unsigned int*)l, 16, 0, 0);
}

// ---------------- prep: swizzled, K-tiled bf16 weights ----------------
// WpTs (BK=32 tiling): [t<24][n<512][q<4][e<8], q = c ^ ((n>>1)&3),
//   value = bf16(Wproj[(t*32 + c*8 + e)*512 + n])
// W1Ts (BK=64 tiling, unchanged): [t<8][n<384][cs<8][e<8], cs = c ^ (n&7),
//   value = bf16(W1[(t*64 + c*8 + e)*384 + n])
__global__ __launch_bounds__(256) void k_prep(
    const float* __restrict__ Wproj, const float* __restrict__ W1,
    unsigned short* __restrict__ WpTs, unsigned short* __restrict__ W1Ts)
{
    const int idx = blockIdx.x * 256 + threadIdx.x;
    if (idx < 49152) {                 // 24*4*512
        const int t = idx >> 11, r = idx & 2047;
        const int c = r >> 9, n = r & 511;
        short8_t v;
        #pragma unroll
        for (int e = 0; e < 8; ++e)
            v[e] = (short)f2bf(Wproj[(size_t)(t * 32 + c * 8 + e) * DIMEMB + n]);
        *(short8_t*)&WpTs[t * 16384 + n * 32 + ((c ^ ((n >> 1) & 3)) << 3)] = v;
    } else {
        const int j = idx - 49152;     // < 24576 = 8*8*384
        const int t = j / 3072, r = j % 3072;
        const int c = r / 384, n = r % 384;
        short8_t v;
        #pragma unroll
        for (int e = 0; e < 8; ++e)
            v[e] = (short)f2bf(W1[(size_t)(t * 64 + c * 8 + e) * DIMATTN + n]);
        *(short8_t*)&W1Ts[t * 24576 + n * 64 + ((c ^ (n & 7)) << 3)] = v;
    }
}

// ---------------- GEMM1: H = relu(X @ Wp + b); BM=128, BN=512, BK=32 ----------------
// counted-vmcnt pipeline: X-loads ride across raw s_barrier; B via gll16 dbuf.
// H stored SWIZZLED: (row,col) at row*512 + (col>>6)*64 + ((((col>>3)&7) ^ (row&7))<<3) + (col&7)
__global__ __launch_bounds__(512, 2) void k_gemm1(
    const float* __restrict__ X,
    const unsigned short* __restrict__ WpTs,
    const float* __restrict__ bproj,
    unsigned short* __restrict__ H)
{
    __shared__ unsigned short As[2][4096];    // 128 x 32 bf16, granule-swizzled
    __shared__ unsigned short Bs[2][16384];   // 512 x 32 bf16, pre-swizzled global
    const int tid = threadIdx.x;
    const int lane = tid & 63, w = tid >> 6;
    const int wr = w >> 2, wc = w & 3;        // 2x4 waves: 64 rows x 128 cols each
    const int g = lane >> 4, fr = lane & 15;
    const int brow = blockIdx.x * 128;

    // A staging: thread -> row tid>>2, k-granule tid&3 (8 fp32 = 32B)
    const int arow = tid >> 2;
    int agr = brow + arow; if (agr >= KINST) agr = KINST - 1;
    const float* xsrc = X + (size_t)agr * DIMIN + (tid & 3) * 8;
    const int awidx = arow * 32 + (((tid & 3) ^ ((tid >> 3) & 3)) << 3);

    // B staging: wave w stages rows [w*64, w*64+64) per step: 4 x gll16
    const unsigned short* gB = WpTs + (size_t)(w * 64 + (lane >> 2)) * 32 + (lane & 3) * 8;
    const int bdidx = w * 2048 + lane * 8;

    // fragment read offset (same XOR for A and B): q = g ^ ((fr>>1)&3)
    const int aq = (g ^ ((fr >> 1) & 3)) << 3;

    f32x4 acc[4][8] = {};
    float4 xva, xvb;

    // ---- prologue: X(0), B(0), X(1); write A(0); counted drain; barrier ----
    {
        float4 fa = *(const float4*)(xsrc);
        float4 fb = *(const float4*)(xsrc + 4);
        __builtin_amdgcn_sched_barrier(0);
        #pragma unroll
        for (int q = 0; q < 4; ++q) gll16(gB + q * 512, &Bs[0][bdidx + q * 512]);
        __builtin_amdgcn_sched_barrier(0);
        xva = *(const float4*)(xsrc + 32);
        xvb = *(const float4*)(xsrc + 36);
        __builtin_amdgcn_sched_barrier(0);
        u32x4 p;
        p[0] = packbf(fa.x, fa.y); p[1] = packbf(fa.z, fa.w);
        p[2] = packbf(fb.x, fb.y); p[3] = packbf(fb.z, fb.w);
        *(u32x4*)&As[0][awidx] = p;
    }
    asm volatile("s_waitcnt vmcnt(2) lgkmcnt(0)" ::: "memory");
    __builtin_amdgcn_sched_barrier(0);
    __builtin_amdgcn_s_barrier();
    __builtin_amdgcn_sched_barrier(0);

    // ---- steady loop t = 0..21 ----
    #pragma unroll 2
    for (int t = 0; t < 22; ++t) {
        const int b = t & 1;
        // 1. issue B(t+1) -> Bs[b^1] (all waves past barrier; b^1 free)
        const unsigned short* gBt = gB + (size_t)(t + 1) * 16384;
        unsigned short* bdst = &Bs[b ^ 1][bdidx];
        #pragma unroll
        for (int q = 0; q < 4; ++q) gll16(gBt + q * 512, bdst + q * 512);
        __builtin_amdgcn_sched_barrier(0);
        // 2. convert + write A(t+1) (compiler waits xv's vmcnt here)
        {
            u32x4 p;
            p[0] = packbf(xva.x, xva.y); p[1] = packbf(xva.z, xva.w);
            p[2] = packbf(xvb.x, xvb.y); p[3] = packbf(xvb.z, xvb.w);
            *(u32x4*)&As[b ^ 1][awidx] = p;
        }
        __builtin_amdgcn_sched_barrier(0);
        // 3. issue X(t+2) — rides across the barrier below
        xva = *(const float4*)(xsrc + (t + 2) * 32);
        xvb = *(const float4*)(xsrc + (t + 2) * 32 + 4);
        __builtin_amdgcn_sched_barrier(0);
        // 4. fragment reads
        short8_t af[4], bf[8];
        #pragma unroll
        for (int i = 0; i < 4; ++i)
            af[i] = *(const short8_t*)&As[b][(wr * 64 + i * 16 + fr) * 32 + aq];
        #pragma unroll
        for (int j = 0; j < 8; ++j)
            bf[j] = *(const short8_t*)&Bs[b][(wc * 128 + j * 16 + fr) * 32 + aq];
        // 5. MFMA
        __builtin_amdgcn_s_setprio(1);
        #pragma unroll
        for (int j = 0; j < 8; ++j)
            #pragma unroll
            for (int i = 0; i < 4; ++i)
                acc[i][j] = __builtin_amdgcn_mfma_f32_16x16x32_bf16(af[i], bf[j], acc[i][j], 0, 0, 0);
        __builtin_amdgcn_s_setprio(0);
        // 6. counted drain: wait the 4 gll16 (B(t+1)) + own ds ops; X(t+2) stays in flight
        asm volatile("s_waitcnt vmcnt(2) lgkmcnt(0)" ::: "memory");
        __builtin_amdgcn_sched_barrier(0);
        __builtin_amdgcn_s_barrier();
        __builtin_amdgcn_sched_barrier(0);
    }

    // ---- t = 22 (write A(23), stage B(23); no more X issues) ----
    {
        const unsigned short* gBt = gB + (size_t)23 * 16384;
        unsigned short* bdst = &Bs[1][bdidx];
        #pragma unroll
        for (int q = 0; q < 4; ++q) gll16(gBt + q * 512, bdst + q * 512);
        __builtin_amdgcn_sched_barrier(0);
        {
            u32x4 p;
            p[0] = packbf(xva.x, xva.y); p[1] = packbf(xva.z, xva.w);
            p[2] = packbf(xvb.x, xvb.y); p[3] = packbf(xvb.z, xvb.w);
            *(u32x4*)&As[1][awidx] = p;
        }
        short8_t af[4], bf[8];
        #pragma unroll
        for (int i = 0; i < 4; ++i)
            af[i] = *(const short8_t*)&As[0][(wr * 64 + i * 16 + fr) * 32 + aq];
        #pragma unroll
        for (int j = 0; j < 8; ++j)
            bf[j] = *(const short8_t*)&Bs[0][(wc * 128 + j * 16 + fr) * 32 + aq];
        __builtin_amdgcn_s_setprio(1);
        #pragma unroll
        for (int j = 0; j < 8; ++j)
            #pragma unroll
            for (int i = 0; i < 4; ++i)
                acc[i][j] = __builtin_amdgcn_mfma_f32_16x16x32_bf16(af[i], bf[j], acc[i][j], 0, 0, 0);
        __builtin_amdgcn_s_setprio(0);
        asm volatile("s_waitcnt vmcnt(0) lgkmcnt(0)" ::: "memory");
        __builtin_amdgcn_sched_barrier(0);
        __builtin_amdgcn_s_barrier();
        __builtin_amdgcn_sched_barrier(0);
    }
    // ---- t = 23 (last compute, no staging) ----
    {
        short8_t af[4], bf[8];
        #pragma unroll
        for (int i = 0; i < 4; ++i)
            af[i] = *(const short8_t*)&As[1][(wr * 64 + i * 16 + fr) * 32 + aq];
        #pragma unroll
        for (int j = 0; j < 8; ++j)
            bf[j] = *(const short8_t*)&Bs[1][(wc * 128 + j * 16 + fr) * 32 + aq];
        #pragma unroll
        for (int j = 0; j < 8; ++j)
            #pragma unroll
            for (int i = 0; i < 4; ++i)
                acc[i][j] = __builtin_amdgcn_mfma_f32_16x16x32_bf16(af[i], bf[j], acc[i][j], 0, 0, 0);
    }

    // ---- epilogue: bias + relu, swizzled bf16 H store ----
    #pragma unroll
    for (int j = 0; j < 8; ++j) {
        const int col = wc * 128 + j * 16 + fr;
        const float bias = bproj[col];
        const int tile = (col >> 6) << 6, cc = (col >> 3) & 7, lo = col & 7;
        #pragma unroll
        for (int i = 0; i < 4; ++i) {
            const int rb = brow + wr * 64 + i * 16 + g * 4;
            #pragma unroll
            for (int r = 0; r < 4; ++r) {
                const int row = rb + r;
                const float v = fmaxf(acc[i][j][r] + bias, 0.f);
                H[(size_t)row * DIMEMB + tile + (((cc ^ (row & 7))) << 3) + lo] =
                    (row < KINST) ? f2bf(v) : (unsigned short)0;
            }
        }
    }
}

// -------- GEMM2 partial scores (unchanged, round-4 verified) --------
__global__ __launch_bounds__(256) void k_gemm2(
    const unsigned short* __restrict__ H,
    const unsigned short* __restrict__ W1Ts,
    const float* __restrict__ b1,
    const float* __restrict__ W2,
    float* __restrict__ Tpart)
{
    __shared__ unsigned short As[2][8192];
    __shared__ unsigned short Bs[2][8192];
    __shared__ float sred[2][128];
    const int tid = threadIdx.x;
    const int lane = tid & 63, w = tid >> 6;
    const int wr = w >> 1, wc = w & 1;
    const int g = lane >> 4, fr = lane & 15;
    const int cb = blockIdx.x;               // 0..2
    const int brow = blockIdx.y * 128;
    const int bcol = cb * 128;

    const unsigned short* gA = H + (size_t)(brow + w * 32 + (lane >> 3)) * DIMEMB + (lane & 7) * 8;
    const unsigned short* gB = W1Ts + (size_t)(bcol + w * 32 + (lane >> 3)) * 64 + (lane & 7) * 8;
    const int loff = w * 2048 + lane * 8;

    f32x4 acc[4][4] = {};

    #pragma unroll
    for (int q = 0; q < 4; ++q) {
        gll16(gA + q * 4096, &As[0][loff + q * 512]);
        gll16(gB + q * 512,  &Bs[0][loff + q * 512]);
    }
    __syncthreads();

    for (int t = 0; t < 8; ++t) {
        const int buf = t & 1;
        if (t < 7) {
            #pragma unroll
            for (int q = 0; q < 4; ++q) {
                gll16(gA + (t + 1) * 64 + q * 4096,          &As[buf ^ 1][loff + q * 512]);
                gll16(gB + (size_t)(t + 1) * 24576 + q * 512, &Bs[buf ^ 1][loff + q * 512]);
            }
        }
        __builtin_amdgcn_s_setprio(1);
        #pragma unroll
        for (int kk = 0; kk < 2; ++kk) {
            short8_t af[4];
            #pragma unroll
            for (int i = 0; i < 4; ++i) {
                const int row = wr * 64 + i * 16 + fr;
                af[i] = *(const short8_t*)&As[buf][row * 64 + (((kk * 4 + g) ^ (fr & 7)) << 3)];
            }
            #pragma unroll
            for (int j = 0; j < 4; ++j) {
                const int rowb = wc * 64 + j * 16 + fr;
                const short8_t bf = *(const short8_t*)&Bs[buf][rowb * 64 + (((kk * 4 + g) ^ (fr & 7)) << 3)];
                #pragma unroll
                for (int i = 0; i < 4; ++i)
                    acc[i][j] = __builtin_amdgcn_mfma_f32_16x16x32_bf16(af[i], bf, acc[i][j], 0, 0, 0);
            }
        }
        __builtin_amdgcn_s_setprio(0);
        if (t < 7) __syncthreads();
    }

    float ps[4][4] = {};
    #pragma unroll
    for (int j = 0; j < 4; ++j) {
        const int col = bcol + wc * 64 + j * 16 + fr;
        const float bb = b1[col], ww = W2[col];
        #pragma unroll
        for (int i = 0; i < 4; ++i)
            #pragma unroll
            for (int r = 0; r < 4; ++r)
                ps[i][r] += fast_tanh(acc[i][j][r] + bb) * ww;
    }
    #pragma unroll
    for (int off = 1; off < 16; off <<= 1)
        #pragma unroll
        for (int i = 0; i < 4; ++i)
            #pragma unroll
            for (int r = 0; r < 4; ++r)
                ps[i][r] += __shfl_xor(ps[i][r], off, 64);
    if (fr == 0) {
        #pragma unroll
        for (int i = 0; i < 4; ++i)
            #pragma unroll
            for (int r = 0; r < 4; ++r)
                sred[wc][wr * 64 + i * 16 + g * 4 + r] = ps[i][r];
    }
    __syncthreads();
    if (tid < 128)
        Tpart[(size_t)cb * KPAD + brow + tid] = sred[0][tid] + sred[1][tid];
}

// ---------------- poolE (unchanged, round-4 verified) ----------------
__global__ __launch_bounds__(512) void k_poolE(
    const float* __restrict__ Tpart,
    const unsigned short* __restrict__ H,
    const float* __restrict__ b2,
    float* __restrict__ Spart,
    float* __restrict__ Mpart)
{
    __shared__ float Elds[1024];
    __shared__ float red[8][512];
    __shared__ float ssum[8];
    const int tid = threadIdx.x, lane = tid & 63, w = tid >> 6;
    const int base = blockIdx.x * 1024;
    const float bb = b2[0];
    float es = 0.f;
    #pragma unroll
    for (int u = 0; u < 2; ++u) {
        const int r = base + u * 512 + tid;
        float e = 0.f;
        if (r < KINST)
            e = __expf(Tpart[r] + Tpart[KPAD + r] + Tpart[2 * KPAD + r] + bb);
        Elds[u * 512 + tid] = e;
        es += e;
    }
    #pragma unroll
    for (int off = 1; off < 64; off <<= 1) es += __shfl_xor(es, off, 64);
    if (lane == 0) ssum[w] = es;
    __syncthreads();
    if (tid == 0) {
        float t = 0.f;
        #pragma unroll
        for (int i = 0; i < 8; ++i) t += ssum[i];
        Spart[blockIdx.x] = t;
    }

    float pa[8] = {};
    const int tile = (lane >> 3) << 6, cf = lane & 7;
    for (int i = 0; i < 128; ++i) {
        const int lr = i * 8 + w;
        const float e = Elds[lr];
        if (e != 0.f) {
            const int r = base + lr;
            const short8_t v = *(const short8_t*)(H + (size_t)r * DIMEMB + tile + ((cf ^ (r & 7)) << 3));
            #pragma unroll
            for (int j = 0; j < 8; ++j) pa[j] += e * bf2f((unsigned short)v[j]);
        }
    }
    #pragma unroll
    for (int j = 0; j < 8; ++j) red[w][lane * 8 + j] = pa[j];
    __syncthreads();
    float s2 = 0.f;
    #pragma unroll
    for (int k = 0; k < 8; ++k) s2 += red[k][tid];
    Mpart[(size_t)blockIdx.x * DIMEMB + tid] = s2;
}

// ---------------- head (unchanged, round-4 verified) ----------------
__global__ __launch_bounds__(512) void k_head(
    const float* __restrict__ Spart,   // [98]
    const float* __restrict__ Mpart,   // [98][512]
    const float* __restrict__ Wr,      // [512][13]
    const float* __restrict__ Xtfl,    // [13][512]
    const float* __restrict__ Wp,      // [512][2]
    const float* __restrict__ bp,      // [2]
    float* __restrict__ outp)
{
    __shared__ float Mlds[512];
    __shared__ float logits[13];
    __shared__ float wsel[5];
    __shared__ int isel[5];
    __shared__ float Slds;
    __shared__ float swred[8];
    __shared__ float r0s[8], r1s[8];
    const int tid = threadIdx.x, lane = tid & 63, w = tid >> 6;

    float s = 0.f;
    if (tid < 98) s = Spart[tid];
    #pragma unroll
    for (int off = 1; off < 64; off <<= 1) s += __shfl_xor(s, off, 64);
    if (lane == 0) swred[w] = s;

    float m = 0.f;
    #pragma unroll 2
    for (int b = 0; b < 98; ++b) m += Mpart[(size_t)b * 512 + tid];

    __syncthreads();
    if (tid == 0) {
        float t = 0.f;
        #pragma unroll
        for (int i = 0; i < 8; ++i) t += swred[i];
        Slds = t;
    }
    __syncthreads();
    Mlds[tid] = m / Slds;
    __syncthreads();
    if (tid < 13) {
        float l = 0.f;
        for (int dd = 0; dd < 512; ++dd) l += Mlds[dd] * Wr[dd * 13 + tid];
        logits[tid] = l;
    }
    __syncthreads();
    if (tid == 0) {
        float mx = -1e30f;
        for (int i = 0; i < 13; ++i) mx = fmaxf(mx, logits[i]);
        float pe[13]; float sum = 0.f;
        for (int i = 0; i < 13; ++i) { pe[i] = __expf(logits[i] - mx); sum += pe[i]; }
        unsigned used = 0;
        for (int t = 0; t < 5; ++t) {
            int bi = 0; float bv = -1.f;
            for (int i = 0; i < 13; ++i)
                if (!((used >> i) & 1u) && pe[i] > bv) { bv = pe[i]; bi = i; }
            used |= (1u << bi);
            wsel[t] = bv / sum;
            isel[t] = bi;
        }
    }
    __syncthreads();
    float mo = 0.f;
    #pragma unroll
    for (int t = 0; t < 5; ++t) mo += wsel[t] * Xtfl[isel[t] * 512 + tid];
    float p0 = mo * Wp[tid * 2 + 0];
    float p1 = mo * Wp[tid * 2 + 1];
    #pragma unroll
    for (int off = 1; off < 64; off <<= 1) {
        p0 += __shfl_xor(p0, off, 64);
        p1 += __shfl_xor(p1, off, 64);
    }
    if (lane == 0) { r0s[w] = p0; r1s[w] = p1; }
    __syncthreads();
    if (tid == 0) {
        float a = bp[0], b = bp[1];
        for (int i = 0; i < 8; ++i) { a += r0s[i]; b += r1s[i]; }
        outp[0] = a; outp[1] = b;
    }
}

extern "C" void kernel_launch(void* const* d_in, const int* in_sizes, int n_in,
                              void* d_out, int out_size, void* d_ws, size_t ws_size,
                              hipStream_t stream)
{
    const float* Xtfl  = (const float*)d_in[0];
    const float* X     = (const float*)d_in[1];
    const float* Wproj = (const float*)d_in[2];
    const float* bproj = (const float*)d_in[3];
    const float* W1    = (const float*)d_in[4];
    const float* b1    = (const float*)d_in[5];
    const float* W2    = (const float*)d_in[6];
    const float* b2    = (const float*)d_in[7];
    const float* Wr    = (const float*)d_in[8];
    const float* Wp    = (const float*)d_in[9];
    const float* bp    = (const float*)d_in[10];
    float* out = (float*)d_out;

    // ws layout (~105 MiB total)
    char* ws = (char*)d_ws;
    size_t off = 0;
    unsigned short* H    = (unsigned short*)(ws + off); off += (size_t)KPAD * DIMEMB * 2;
    unsigned short* WpTs = (unsigned short*)(ws + off); off += (size_t)DIMEMB * DIMIN * 2;
    unsigned short* W1Ts = (unsigned short*)(ws + off); off += (size_t)DIMATTN * DIMEMB * 2;
    float* Tpart = (float*)(ws + off); off += (size_t)3 * KPAD * 4;
    float* Spart = (float*)(ws + off); off += 1024;
    float* Mpart = (float*)(ws + off); off += (size_t)98 * DIMEMB * 4;

    k_prep<<<288, 256, 0, stream>>>(Wproj, W1, WpTs, W1Ts);
    k_gemm1<<<782, 512, 0, stream>>>(X, WpTs, bproj, H);
    k_gemm2<<<dim3(3, 782), 256, 0, stream>>>(H, W1Ts, b1, W2, Tpart);
    k_poolE<<<98, 512, 0, stream>>>(Tpart, H, b2, Spart, Mpart);
    k_head<<<1, 512, 0, stream>>>(Spart, Mpart, Wr, Xtfl, Wp, bp, out);
}